// Round 1
// baseline (188.819 us; speedup 1.0000x reference)
//
#include <hip/hip_runtime.h>

#define HD 32
#define NHEADS 12
#define HH 56
#define WW 56
#define NN (HH * WW)
#define BB 8
#define CC (HD * NHEADS)

__global__ __launch_bounds__(256) void dilate_attn_kernel(
    const float* __restrict__ q,
    const float* __restrict__ k,
    const float* __restrict__ v,
    float* __restrict__ out)
{
    const int n = blockIdx.x * blockDim.x + threadIdx.x;
    if (n >= NN) return;
    const int bh = blockIdx.y;
    const int b = bh / NHEADS;
    const int head = bh - b * NHEADS;
    const int y = n / WW;
    const int x = n - y * WW;

    const size_t base = ((size_t)b * CC + (size_t)head * HD) * NN;
    const float* qb = q + base + n;

    // q fragment: coalesced (lane i -> n+i contiguous) per channel
    float qv[HD];
#pragma unroll
    for (int d = 0; d < HD; ++d) qv[d] = qb[(size_t)d * NN];

    // QK^T logits over the 9 dilated taps. Zero-padded unfold => OOB logit = 0.
    float lg[9];
#pragma unroll
    for (int kk = 0; kk < 9; ++kk) {
        const int dy = ((kk / 3) - 1) * 2;
        const int dx = ((kk % 3) - 1) * 2;
        const int ny = y + dy;
        const int nx = x + dx;
        float s = 0.f;
        if ((unsigned)ny < HH && (unsigned)nx < WW) {
            const float* kb = k + base + (size_t)(ny * WW + nx);
#pragma unroll
            for (int d = 0; d < HD; ++d) s = fmaf(qv[d], kb[(size_t)d * NN], s);
        }
        lg[kk] = s * 0.17677669529663689f;  // 32^-0.5
    }

    // softmax over 9 (OOB logits participate with value 0, matching reference)
    float m = lg[0];
#pragma unroll
    for (int kk = 1; kk < 9; ++kk) m = fmaxf(m, lg[kk]);
    float wsum = 0.f;
#pragma unroll
    for (int kk = 0; kk < 9; ++kk) { lg[kk] = __expf(lg[kk] - m); wsum += lg[kk]; }
    const float inv = 1.f / wsum;

    // PV accumulate (OOB taps contribute zero V)
    float acc[HD];
#pragma unroll
    for (int d = 0; d < HD; ++d) acc[d] = 0.f;
#pragma unroll
    for (int kk = 0; kk < 9; ++kk) {
        const int dy = ((kk / 3) - 1) * 2;
        const int dx = ((kk % 3) - 1) * 2;
        const int ny = y + dy;
        const int nx = x + dx;
        if ((unsigned)ny < HH && (unsigned)nx < WW) {
            const float w = lg[kk] * inv;
            const float* vb = v + base + (size_t)(ny * WW + nx);
#pragma unroll
            for (int d = 0; d < HD; ++d) acc[d] = fmaf(w, vb[(size_t)d * NN], acc[d]);
        }
    }

    // out[b, y, x, head*32 + d] : 32 contiguous floats = one aligned 128B line
    float* ob = out + (((size_t)b * HH + y) * WW + x) * CC + (size_t)head * HD;
#pragma unroll
    for (int d = 0; d < HD; d += 4) {
        float4 val = make_float4(acc[d], acc[d + 1], acc[d + 2], acc[d + 3]);
        *reinterpret_cast<float4*>(ob + d) = val;
    }
}

extern "C" void kernel_launch(void* const* d_in, const int* in_sizes, int n_in,
                              void* d_out, int out_size, void* d_ws, size_t ws_size,
                              hipStream_t stream) {
    const float* q = (const float*)d_in[0];
    const float* k = (const float*)d_in[1];
    const float* v = (const float*)d_in[2];
    float* out = (float*)d_out;

    dim3 block(256);
    dim3 grid((NN + 255) / 256, BB * NHEADS);
    dilate_attn_kernel<<<grid, block, 0, stream>>>(q, k, v, out);
}

// Round 2
// 185.172 us; speedup vs baseline: 1.0197x; 1.0197x over previous
//
#include <hip/hip_runtime.h>

#define HD 32
#define HALF 16
#define NHEADS 12
#define HH 56
#define WW 56
#define NN (HH * WW)
#define BB 8
#define CC (HD * NHEADS)
#define TILE_N 128   // n positions per block
#define SCALE 0.17677669529663689f

// block: (128, 2) = 256 threads. threadIdx.x -> n within tile (coalesced),
// threadIdx.y -> channel half (16 channels each). Partial QK dots combined
// via LDS; softmax duplicated per half (9-wide, cheap); PV per half.
__global__ __launch_bounds__(256) void dilate_attn_kernel(
    const float* __restrict__ q,
    const float* __restrict__ k,
    const float* __restrict__ v,
    float* __restrict__ out)
{
    const int xi = threadIdx.x;            // 0..127
    const int half = threadIdx.y;          // 0..1
    const int n = blockIdx.x * TILE_N + xi;
    const int bh = blockIdx.y;
    const int b = bh / NHEADS;
    const int head = bh - b * NHEADS;
    const bool active = (n < NN);

    const int y = n / WW;
    const int x = n - y * WW;

    // base for this thread's 16 channels
    const size_t base = ((size_t)b * CC + (size_t)head * HD + (size_t)half * HALF) * NN;

    __shared__ float part[2][TILE_N][9];   // 9216 B; stride-9 floats -> 2 lanes/bank (free)

    // q fragment (16 channels), coalesced: lane i -> n+i
    float qv[HALF];
    if (active) {
        const float* qb = q + base + n;
#pragma unroll
        for (int d = 0; d < HALF; ++d) qv[d] = qb[(size_t)d * NN];
    }

    // partial QK logits over 9 dilated taps (zero-padded unfold => OOB logit 0)
    float lg[9];
#pragma unroll
    for (int t = 0; t < 9; ++t) {
        const int dy = ((t / 3) - 1) * 2;
        const int dx = ((t % 3) - 1) * 2;
        const int ny = y + dy;
        const int nx = x + dx;
        float s = 0.f;
        if (active && (unsigned)ny < HH && (unsigned)nx < WW) {
            const float* kb = k + base + (size_t)(ny * WW + nx);
#pragma unroll
            for (int d = 0; d < HALF; ++d) s = fmaf(qv[d], kb[(size_t)d * NN], s);
        }
        lg[t] = s;
        part[half][xi][t] = s;
    }
    __syncthreads();

    // combine halves, scale, softmax over 9 (both halves duplicate this)
    {
        const int other = 1 - half;
#pragma unroll
        for (int t = 0; t < 9; ++t)
            lg[t] = (lg[t] + part[other][xi][t]) * SCALE;
    }
    float m = lg[0];
#pragma unroll
    for (int t = 1; t < 9; ++t) m = fmaxf(m, lg[t]);
    float wsum = 0.f;
#pragma unroll
    for (int t = 0; t < 9; ++t) { lg[t] = __expf(lg[t] - m); wsum += lg[t]; }
    const float inv = 1.f / wsum;

    // PV accumulate over this half's 16 channels
    float acc[HALF];
#pragma unroll
    for (int d = 0; d < HALF; ++d) acc[d] = 0.f;
#pragma unroll
    for (int t = 0; t < 9; ++t) {
        const int dy = ((t / 3) - 1) * 2;
        const int dx = ((t % 3) - 1) * 2;
        const int ny = y + dy;
        const int nx = x + dx;
        if (active && (unsigned)ny < HH && (unsigned)nx < WW) {
            const float w = lg[t] * inv;
            const float* vb = v + base + (size_t)(ny * WW + nx);
#pragma unroll
            for (int d = 0; d < HALF; ++d) acc[d] = fmaf(w, vb[(size_t)d * NN], acc[d]);
        }
    }

    // out[b, y, x, head*32 + half*16 + d] : 16 contiguous floats (4x float4)
    if (active) {
        float* ob = out + (((size_t)b * HH + y) * WW + x) * CC
                    + (size_t)head * HD + (size_t)half * HALF;
#pragma unroll
        for (int d = 0; d < HALF; d += 4) {
            float4 val = make_float4(acc[d], acc[d + 1], acc[d + 2], acc[d + 3]);
            *reinterpret_cast<float4*>(ob + d) = val;
        }
    }
}

extern "C" void kernel_launch(void* const* d_in, const int* in_sizes, int n_in,
                              void* d_out, int out_size, void* d_ws, size_t ws_size,
                              hipStream_t stream) {
    const float* q = (const float*)d_in[0];
    const float* k = (const float*)d_in[1];
    const float* v = (const float*)d_in[2];
    float* out = (float*)d_out;

    dim3 block(TILE_N, 2);
    dim3 grid((NN + TILE_N - 1) / TILE_N, BB * NHEADS);
    dilate_attn_kernel<<<grid, block, 0, stream>>>(q, k, v, out);
}